// Round 2
// baseline (10501.962 us; speedup 1.0000x reference)
//
#include <hip/hip_runtime.h>

// ---------------- problem constants ----------------
#define MUL0 64
#define MUL1 32
#define NBASIS 10
#define FCH 100
#define WNUMEL 224   // 2*MUL0 + 3*MUL1
#define MIDS 96      // MUL0 + MUL1
#define MIDV 128     // MUL0 + 2*MUL1

// weight table offsets inside ws (floats), in d_in[7..15] order
#define OFF_W1   0        // W_fc1  10x100  (1000)
#define OFF_W2   1000     // W_fc2  100x224 (22400)
#define OFF_WSCS 23400    // W_sc_s 64x64   (4096)
#define OFF_WSCV 27496    // W_sc_v 32x32   (1024)
#define OFF_WL1S 28520    // W_l1_s 64x64   (4096)
#define OFF_WL1V 32616    // W_l1_v 32x32   (1024)
#define OFF_WL2S 33640    // W_l2_s 96x64   (6144)
#define OFF_WL2V 39784    // W_l2_v 128x32  (4096)
#define OFF_WL3  43880    // W_l3   96x1    (96)
#define OFF_WEND 43976
#define OFF_FLAG 43980    // dtype flag (int) lives here, inside the pad
#define OFF_DYN  44032    // padded start of per-node buffers

// ---------------- helpers ----------------
__device__ __forceinline__ float bf2f(unsigned short h) {
    unsigned int u = ((unsigned int)h) << 16;
    float f; __builtin_memcpy(&f, &u, 4); return f;
}
__device__ __forceinline__ unsigned short f2bf(float f) {
    unsigned int u; __builtin_memcpy(&u, &f, 4);
    u += 0x7fffu + ((u >> 16) & 1u);   // round-to-nearest-even
    return (unsigned short)(u >> 16);
}
__device__ __forceinline__ float lo2f(unsigned int w) {
    unsigned int u = w << 16; float f; __builtin_memcpy(&f, &u, 4); return f;
}
__device__ __forceinline__ float hi2f(unsigned int w) {
    unsigned int u = w & 0xffff0000u; float f; __builtin_memcpy(&f, &u, 4); return f;
}
__device__ __forceinline__ float fast_silu(float x) {
    return x * __builtin_amdgcn_rcpf(1.0f + __expf(-x));
}
// dtype-generic load/store: BF=true -> bf16 stream, BF=false -> fp32 stream
template<bool BF>
__device__ __forceinline__ float ldf(const void* p, size_t i) {
    if constexpr (BF) return bf2f(((const unsigned short*)p)[i]);
    else              return ((const float*)p)[i];
}
template<bool BF>
__device__ __forceinline__ void stf(void* p, size_t i, float v) {
    if constexpr (BF) ((unsigned short*)p)[i] = f2bf(v);
    else              ((float*)p)[i] = v;
}

// ---------------- kernel P: dtype probe ----------------
// node_attr is all-ones: first u32 word is 0x3F800000 (fp32) or 0x3F803F80 (bf16)
__global__ void k_probe(const unsigned int* __restrict__ attr_bits, int* __restrict__ flag)
{
    if (blockIdx.x == 0 && threadIdx.x == 0)
        *flag = (attr_bits[0] == 0x3F803F80u) ? 1 : 0;
}

// ---------------- kernel 0: convert all weights -> fp32 in ws ----------------
__global__ __launch_bounds__(256) void k_convert(
    const void* __restrict__ a0, const void* __restrict__ a1,
    const void* __restrict__ a2, const void* __restrict__ a3,
    const void* __restrict__ a4, const void* __restrict__ a5,
    const void* __restrict__ a6, const void* __restrict__ a7,
    const void* __restrict__ a8, float* __restrict__ wsf,
    const int* __restrict__ flag)
{
    int i = blockIdx.x * 256 + threadIdx.x;
    if (i >= OFF_WEND) return;
    const void* p; int off = i;
    if      (i < OFF_W2)   { p = a0; }
    else if (i < OFF_WSCS) { p = a1; off = i - OFF_W2; }
    else if (i < OFF_WSCV) { p = a2; off = i - OFF_WSCS; }
    else if (i < OFF_WL1S) { p = a3; off = i - OFF_WSCV; }
    else if (i < OFF_WL1V) { p = a4; off = i - OFF_WL1S; }
    else if (i < OFF_WL2S) { p = a5; off = i - OFF_WL1V; }
    else if (i < OFF_WL2V) { p = a6; off = i - OFF_WL2S; }
    else if (i < OFF_WL3)  { p = a7; off = i - OFF_WL2V; }
    else                   { p = a8; off = i - OFF_WL3; }
    wsf[i] = (*flag) ? ldf<true>(p, off) : ldf<false>(p, off);
}

// ---------------- kernel 1: node precompute f_s, f_v ----------------
template<bool BF>
__device__ __forceinline__ void node_pre_body(
    const void* __restrict__ ns, const void* __restrict__ nv,
    const void* __restrict__ attr,
    const float* __restrict__ Wl1s, const float* __restrict__ Wl1v,
    float* __restrict__ f_s, float* __restrict__ f_v, int Nn)
{
    int i = blockIdx.x * 256 + threadIdx.x;
    int stotal = Nn * MUL0;
    if (i < stotal) {
        int n = i >> 6, j = i & 63;
        float a = 0.f;
        #pragma unroll
        for (int u = 0; u < MUL0; u++)
            a = fmaf(ldf<BF>(ns, (size_t)n * MUL0 + u), Wl1s[u * MUL0 + j], a);
        f_s[i] = a * ldf<BF>(attr, n);
    } else {
        int m = i - stotal;
        if (m >= Nn * MUL1 * 3) return;
        int n = m / 96; int idx = m - n * 96;
        int vi = idx / 3; int c = idx - vi * 3;
        float a = 0.f;
        #pragma unroll
        for (int u = 0; u < MUL1; u++)
            a = fmaf(ldf<BF>(nv, (size_t)n * 96 + u * 3 + c), Wl1v[u * MUL1 + vi], a);
        f_v[m] = a * ldf<BF>(attr, n);
    }
}
__global__ __launch_bounds__(256) void k_node_pre(
    const void* ns, const void* nv, const void* attr,
    const float* Wl1s, const float* Wl1v,
    float* f_s, float* f_v, int Nn, const int* flag)
{
    if (*flag) node_pre_body<true >(ns, nv, attr, Wl1s, Wl1v, f_s, f_v, Nn);
    else       node_pre_body<false>(ns, nv, attr, Wl1s, Wl1v, f_s, f_v, Nn);
}

// ---------------- kernel 2: fused edge kernel ----------------
__global__ __launch_bounds__(256) void k_edge(
    const void* __restrict__ escal,  // E x 10
    const void* __restrict__ eattr,  // E x 4
    const int* __restrict__ esrc, const int* __restrict__ edst,
    const float* __restrict__ W1f,   // 10 x 100
    const float* __restrict__ W2f,   // 100 x 224
    const float* __restrict__ f_s,   // N x 64
    const float* __restrict__ f_v,   // N x 96
    float* __restrict__ agg_s,       // N x 96
    float* __restrict__ agg_v,       // N x 384
    int Ecnt, const int* __restrict__ flag)
{
    __shared__ unsigned int hbuf[50 * 256];   // 50 KB: h[100] as bf16 pairs, column-per-thread
    const int tid = threadIdx.x;
    const int e = blockIdx.x * 256 + tid;
    const bool active = (e < Ecnt);
    const int ee = active ? e : 0;

    const int src = esrc[ee];
    const int dst = edst[ee];

    float es[NBASIS];
    float y0, y1x, y1y, y1z;
    if (*flag) {
        #pragma unroll
        for (int k = 0; k < NBASIS; k++) es[k] = ldf<true>(escal, (size_t)ee * NBASIS + k);
        y0  = ldf<true>(eattr, (size_t)ee * 4 + 0);
        y1x = ldf<true>(eattr, (size_t)ee * 4 + 1);
        y1y = ldf<true>(eattr, (size_t)ee * 4 + 2);
        y1z = ldf<true>(eattr, (size_t)ee * 4 + 3);
    } else {
        #pragma unroll
        for (int k = 0; k < NBASIS; k++) es[k] = ldf<false>(escal, (size_t)ee * NBASIS + k);
        y0  = ldf<false>(eattr, (size_t)ee * 4 + 0);
        y1x = ldf<false>(eattr, (size_t)ee * 4 + 1);
        y1y = ldf<false>(eattr, (size_t)ee * 4 + 2);
        y1z = ldf<false>(eattr, (size_t)ee * 4 + 3);
    }

    // ---- FC1: h = silu(es @ W1), stored to LDS as bf16 pairs ----
#define FC1_CHUNK(JB, CW) do {                                              \
        float acc[CW];                                                      \
        _Pragma("unroll") for (int j = 0; j < CW; j++) acc[j] = 0.f;        \
        _Pragma("unroll") for (int k = 0; k < NBASIS; k++) {                \
            float ek = es[k];                                               \
            _Pragma("unroll") for (int j = 0; j < CW; j++)                  \
                acc[j] = fmaf(ek, W1f[k * FCH + (JB) + j], acc[j]);         \
        }                                                                   \
        _Pragma("unroll") for (int j = 0; j < CW; j += 2) {                 \
            float a = fast_silu(acc[j]);                                    \
            float b = fast_silu(acc[j + 1]);                                \
            hbuf[(((JB) + j) >> 1) * 256 + tid] =                           \
                (unsigned int)f2bf(a) | ((unsigned int)f2bf(b) << 16);      \
        }                                                                   \
    } while (0)

    FC1_CHUNK(0, 32);
    FC1_CHUNK(32, 32);
    FC1_CHUNK(64, 32);
    FC1_CHUNK(96, 4);
#undef FC1_CHUNK

    // ---- FC2 chunk: w[jb..jb+31] = h @ W2[:, jb..jb+31] ----
    float w[32];
    auto fc2_chunk32 = [&](int jb) {
        #pragma unroll
        for (int j = 0; j < 32; j++) w[j] = 0.f;
        for (int p = 0; p < 50; p++) {
            unsigned int hw = hbuf[p * 256 + tid];
            float h0 = lo2f(hw);
            float h1 = hi2f(hw);
            const float* r0 = W2f + (size_t)(2 * p) * WNUMEL + jb;   // uniform -> s_load
            #pragma unroll
            for (int j = 0; j < 32; j++)
                w[j] = fmaf(h0, r0[j], fmaf(h1, r0[WNUMEL + j], w[j]));
        }
    };

    const float invn = 0.25f;                 // 1/sqrt(16)
    const float y0i  = y0 * invn;
    const float* fs_row = f_s + (size_t)src * MUL0;
    const float* fv_row = f_v + (size_t)src * 96;
    float* as_row = agg_s + (size_t)dst * MIDS;
    float* av_row = agg_v + (size_t)dst * (MIDV * 3);

    // Segment A: w00 * s * y0 -> agg_s[0..63]
    for (int j0 = 0; j0 < 64; j0 += 32) {
        fc2_chunk32(j0);
        if (active) {
            #pragma unroll
            for (int j = 0; j < 32; j++) {
                float sv = fs_row[j0 + j];
                atomicAdd(&as_row[j0 + j], w[j] * sv * y0i);
            }
        }
    }
    // Segment B: w01 * s (x) y1 -> agg_v rows 0..63
    for (int j0 = 0; j0 < 64; j0 += 32) {
        fc2_chunk32(64 + j0);
        if (active) {
            #pragma unroll
            for (int j = 0; j < 32; j++) {
                float b = w[j] * fs_row[j0 + j] * invn;
                float* p = av_row + (size_t)(j0 + j) * 3;
                atomicAdd(p + 0, b * y1x);
                atomicAdd(p + 1, b * y1y);
                atomicAdd(p + 2, b * y1z);
            }
        }
    }
    // Segment C: w10 * v * y0 -> agg_v rows 64..95
    {
        fc2_chunk32(128);
        if (active) {
            #pragma unroll
            for (int u = 0; u < 32; u++) {
                float b = w[u] * y0i;
                const float* vp = fv_row + u * 3;
                float* p = av_row + (size_t)(64 + u) * 3;
                atomicAdd(p + 0, b * vp[0]);
                atomicAdd(p + 1, b * vp[1]);
                atomicAdd(p + 2, b * vp[2]);
            }
        }
    }
    // Segment D: w11s * dot(v, y1)/sqrt3 -> agg_s[64..95]
    {
        fc2_chunk32(160);
        const float c3 = 0.25f * 0.57735026918962576451f;
        if (active) {
            #pragma unroll
            for (int u = 0; u < 32; u++) {
                const float* vp = fv_row + u * 3;
                float d = vp[0] * y1x + vp[1] * y1y + vp[2] * y1z;
                atomicAdd(&as_row[64 + u], w[u] * d * c3);
            }
        }
    }
    // Segment E: w11v * cross(v, y1)/sqrt2 -> agg_v rows 96..127
    {
        fc2_chunk32(192);
        const float c2 = 0.25f * 0.70710678118654752440f;
        if (active) {
            #pragma unroll
            for (int u = 0; u < 32; u++) {
                const float* vp = fv_row + u * 3;
                float v0 = vp[0], v1 = vp[1], v2 = vp[2];
                float cx = v1 * y1z - v2 * y1y;
                float cy = v2 * y1x - v0 * y1z;
                float cz = v0 * y1y - v1 * y1x;
                float b = w[u] * c2;
                float* p = av_row + (size_t)(96 + u) * 3;
                atomicAdd(p + 0, b * cx);
                atomicAdd(p + 1, b * cy);
                atomicAdd(p + 2, b * cz);
            }
        }
    }
}

// ---------------- kernel 3: angle -> cos/sin per node ----------------
__global__ __launch_bounds__(256) void k_angle(
    const float* __restrict__ agg_s, const float* __restrict__ Wl3,
    const void* __restrict__ attr,
    float* __restrict__ cosb, float* __restrict__ sinb, int Nn,
    const int* __restrict__ flag)
{
    int n = blockIdx.x * 256 + threadIdx.x;
    if (n >= Nn) return;
    const float* r = agg_s + (size_t)n * MIDS;
    float a = 0.f;
    #pragma unroll
    for (int u = 0; u < MIDS; u++) a = fmaf(r[u], Wl3[u], a);
    float at = (*flag) ? ldf<true>(attr, n) : ldf<false>(attr, n);
    a = 0.1f * a * at;
    cosb[n] = __cosf(a);
    sinb[n] = __sinf(a);
}

// ---------------- kernel 4: final output ----------------
template<bool BF>
__device__ __forceinline__ void final_body(
    const void* __restrict__ ns, const void* __restrict__ nv,
    const void* __restrict__ attr,
    const float* __restrict__ Wscs, const float* __restrict__ Wscv,
    const float* __restrict__ Wl2s, const float* __restrict__ Wl2v,
    const float* __restrict__ agg_s, const float* __restrict__ agg_v,
    const float* __restrict__ cosb, const float* __restrict__ sinb,
    void* __restrict__ out, int Nn)
{
    int i = blockIdx.x * 256 + threadIdx.x;
    int stotal = Nn * MUL0;
    if (i < stotal) {
        int n = i >> 6, j = i & 63;
        const float* ar = agg_s + (size_t)n * MIDS;
        float a1 = 0.f, a2 = 0.f;
        #pragma unroll
        for (int u = 0; u < MUL0; u++)
            a1 = fmaf(ldf<BF>(ns, (size_t)n * MUL0 + u), Wscs[u * MUL0 + j], a1);
        #pragma unroll
        for (int u = 0; u < MIDS; u++) a2 = fmaf(ar[u], Wl2s[u * MUL0 + j], a2);
        float o = ldf<BF>(attr, n) * (cosb[n] * a1 + sinb[n] * a2);
        stf<BF>(out, (size_t)n * 160 + j, o);
    } else {
        int m = i - stotal;
        if (m >= Nn * 96) return;
        int n = m / 96; int idx = m - n * 96;
        int vi = idx / 3; int c = idx - vi * 3;
        const float* ar = agg_v + (size_t)n * (MIDV * 3);
        float a1 = 0.f, a2 = 0.f;
        #pragma unroll
        for (int u = 0; u < MUL1; u++)
            a1 = fmaf(ldf<BF>(nv, (size_t)n * 96 + u * 3 + c), Wscv[u * MUL1 + vi], a1);
        #pragma unroll
        for (int u = 0; u < MIDV; u++) a2 = fmaf(ar[u * 3 + c], Wl2v[u * MUL1 + vi], a2);
        float o = ldf<BF>(attr, n) * (cosb[n] * a1 + sinb[n] * a2);
        stf<BF>(out, (size_t)n * 160 + 64 + idx, o);
    }
}
__global__ __launch_bounds__(256) void k_final(
    const void* ns, const void* nv, const void* attr,
    const float* Wscs, const float* Wscv,
    const float* Wl2s, const float* Wl2v,
    const float* agg_s, const float* agg_v,
    const float* cosb, const float* sinb,
    void* out, int Nn, const int* flag)
{
    if (*flag) final_body<true >(ns, nv, attr, Wscs, Wscv, Wl2s, Wl2v, agg_s, agg_v, cosb, sinb, out, Nn);
    else       final_body<false>(ns, nv, attr, Wscs, Wscv, Wl2s, Wl2v, agg_s, agg_v, cosb, sinb, out, Nn);
}

// ---------------- launch ----------------
extern "C" void kernel_launch(void* const* d_in, const int* in_sizes, int n_in,
                              void* d_out, int out_size, void* d_ws, size_t ws_size,
                              hipStream_t stream)
{
    const void* ns    = d_in[0];
    const void* nv    = d_in[1];
    const void* attr  = d_in[2];
    const int*  esrc  = (const int*)d_in[3];
    const int*  edst  = (const int*)d_in[4];
    const void* eattr = d_in[5];
    const void* escal = d_in[6];

    const int Nn   = in_sizes[2];   // node_attr is (N,1)
    const int Ecnt = in_sizes[3];   // edge_src is (E,)

    float* ws = (float*)d_ws;
    int* flag = (int*)(ws + OFF_FLAG);
    const size_t OFF_FS   = OFF_DYN;
    const size_t OFF_FV   = OFF_FS   + (size_t)Nn * 64;
    const size_t OFF_AGGS = OFF_FV   + (size_t)Nn * 96;
    const size_t OFF_AGGV = OFF_AGGS + (size_t)Nn * 96;
    const size_t OFF_COS  = OFF_AGGV + (size_t)Nn * 384;
    const size_t OFF_SIN  = OFF_COS  + (size_t)Nn;

    // zero the aggregation buffers (agg_s and agg_v are contiguous)
    hipMemsetAsync(ws + OFF_AGGS, 0, (size_t)Nn * 480 * sizeof(float), stream);

    k_probe<<<1, 64, 0, stream>>>((const unsigned int*)attr, flag);

    k_convert<<<(OFF_WEND + 255) / 256, 256, 0, stream>>>(
        d_in[7], d_in[8], d_in[9], d_in[10], d_in[11], d_in[12],
        d_in[13], d_in[14], d_in[15], ws, flag);

    k_node_pre<<<((Nn * 160) + 255) / 256, 256, 0, stream>>>(
        ns, nv, attr, ws + OFF_WL1S, ws + OFF_WL1V,
        ws + OFF_FS, ws + OFF_FV, Nn, flag);

    k_edge<<<(Ecnt + 255) / 256, 256, 0, stream>>>(
        escal, eattr, esrc, edst,
        ws + OFF_W1, ws + OFF_W2,
        ws + OFF_FS, ws + OFF_FV,
        ws + OFF_AGGS, ws + OFF_AGGV, Ecnt, flag);

    k_angle<<<(Nn + 255) / 256, 256, 0, stream>>>(
        ws + OFF_AGGS, ws + OFF_WL3, attr,
        ws + OFF_COS, ws + OFF_SIN, Nn, flag);

    k_final<<<((Nn * 160) + 255) / 256, 256, 0, stream>>>(
        ns, nv, attr,
        ws + OFF_WSCS, ws + OFF_WSCV, ws + OFF_WL2S, ws + OFF_WL2V,
        ws + OFF_AGGS, ws + OFF_AGGV, ws + OFF_COS, ws + OFF_SIN,
        d_out, Nn, flag);
}

// Round 3
// 3276.789 us; speedup vs baseline: 3.2050x; 3.2050x over previous
//
#include <hip/hip_runtime.h>

// ---------------- problem constants ----------------
#define MUL0 64
#define MUL1 32
#define NBASIS 10
#define FCH 100
#define WNUMEL 224   // 2*MUL0 + 3*MUL1
#define MIDS 96      // MUL0 + MUL1
#define MIDV 128     // MUL0 + 2*MUL1
#define GNODES 16    // dst nodes per workgroup in k_edge_agg

// weight table offsets inside ws (floats), in d_in[7..15] order
#define OFF_W1   0        // W_fc1  10x100  (1000)
#define OFF_W2   1000     // W_fc2  100x224 (22400)
#define OFF_WSCS 23400    // W_sc_s 64x64   (4096)
#define OFF_WSCV 27496    // W_sc_v 32x32   (1024)
#define OFF_WL1S 28520    // W_l1_s 64x64   (4096)
#define OFF_WL1V 32616    // W_l1_v 32x32   (1024)
#define OFF_WL2S 33640    // W_l2_s 96x64   (6144)
#define OFF_WL2V 39784    // W_l2_v 128x32  (4096)
#define OFF_WL3  43880    // W_l3   96x1    (96)
#define OFF_WEND 43976
#define OFF_FLAG 43980    // dtype flag (int) lives here, inside the pad
#define OFF_DYN  44032    // padded start of per-node buffers

// ---------------- helpers ----------------
__device__ __forceinline__ float bf2f(unsigned short h) {
    unsigned int u = ((unsigned int)h) << 16;
    float f; __builtin_memcpy(&f, &u, 4); return f;
}
__device__ __forceinline__ unsigned short f2bf(float f) {
    unsigned int u; __builtin_memcpy(&u, &f, 4);
    u += 0x7fffu + ((u >> 16) & 1u);   // round-to-nearest-even
    return (unsigned short)(u >> 16);
}
__device__ __forceinline__ float lo2f(unsigned int w) {
    unsigned int u = w << 16; float f; __builtin_memcpy(&f, &u, 4); return f;
}
__device__ __forceinline__ float hi2f(unsigned int w) {
    unsigned int u = w & 0xffff0000u; float f; __builtin_memcpy(&f, &u, 4); return f;
}
__device__ __forceinline__ float fast_silu(float x) {
    return x * __builtin_amdgcn_rcpf(1.0f + __expf(-x));
}
// dtype-generic load/store: BF=true -> bf16 stream, BF=false -> fp32 stream
template<bool BF>
__device__ __forceinline__ float ldf(const void* p, size_t i) {
    if constexpr (BF) return bf2f(((const unsigned short*)p)[i]);
    else              return ((const float*)p)[i];
}
template<bool BF>
__device__ __forceinline__ void stf(void* p, size_t i, float v) {
    if constexpr (BF) ((unsigned short*)p)[i] = f2bf(v);
    else              ((float*)p)[i] = v;
}

// ---------------- kernel P: dtype probe ----------------
__global__ void k_probe(const unsigned int* __restrict__ attr_bits, int* __restrict__ flag)
{
    if (blockIdx.x == 0 && threadIdx.x == 0)
        *flag = (attr_bits[0] == 0x3F803F80u) ? 1 : 0;
}

// ---------------- kernel 0: convert all weights -> fp32 in ws ----------------
__global__ __launch_bounds__(256) void k_convert(
    const void* __restrict__ a0, const void* __restrict__ a1,
    const void* __restrict__ a2, const void* __restrict__ a3,
    const void* __restrict__ a4, const void* __restrict__ a5,
    const void* __restrict__ a6, const void* __restrict__ a7,
    const void* __restrict__ a8, float* __restrict__ wsf,
    const int* __restrict__ flag)
{
    int i = blockIdx.x * 256 + threadIdx.x;
    if (i >= OFF_WEND) return;
    const void* p; int off = i;
    if      (i < OFF_W2)   { p = a0; }
    else if (i < OFF_WSCS) { p = a1; off = i - OFF_W2; }
    else if (i < OFF_WSCV) { p = a2; off = i - OFF_WSCS; }
    else if (i < OFF_WL1S) { p = a3; off = i - OFF_WSCV; }
    else if (i < OFF_WL1V) { p = a4; off = i - OFF_WL1S; }
    else if (i < OFF_WL2S) { p = a5; off = i - OFF_WL1V; }
    else if (i < OFF_WL2V) { p = a6; off = i - OFF_WL2S; }
    else if (i < OFF_WL3)  { p = a7; off = i - OFF_WL2V; }
    else                   { p = a8; off = i - OFF_WL3; }
    wsf[i] = (*flag) ? ldf<true>(p, off) : ldf<false>(p, off);
}

// ---------------- CSR build: histogram / scan / place ----------------
__global__ __launch_bounds__(256) void k_hist(
    const int* __restrict__ edst, int* __restrict__ cnt, int Ecnt)
{
    int e = blockIdx.x * 256 + threadIdx.x;
    if (e < Ecnt) atomicAdd(&cnt[edst[e]], 1);
}

__device__ __forceinline__ int wave_incl_scan(int v) {
    int lane = threadIdx.x & 63;
    #pragma unroll
    for (int d = 1; d < 64; d <<= 1) {
        int t = __shfl_up(v, d, 64);
        if (lane >= d) v += t;
    }
    return v;
}

// single workgroup, 1024 threads: exclusive scan of cnt -> row_start, zero cur
__global__ __launch_bounds__(1024) void k_scan(
    const int* __restrict__ cnt, int* __restrict__ row_start,
    int* __restrict__ cur, int Nn)
{
    __shared__ int wsum[16];
    __shared__ int s_off, s_tot;
    int tid = threadIdx.x, lane = tid & 63, wid = tid >> 6;
    if (tid == 0) s_off = 0;
    __syncthreads();
    for (int base = 0; base < Nn; base += 1024) {
        int i = base + tid;
        int v = (i < Nn) ? cnt[i] : 0;
        int incl = wave_incl_scan(v);
        if (lane == 63) wsum[wid] = incl;
        __syncthreads();
        if (wid == 0) {
            int wv = (lane < 16) ? wsum[lane] : 0;
            int wincl = wave_incl_scan(wv);
            if (lane < 16) wsum[lane] = wincl - wv;   // exclusive wave offset
            if (lane == 15) s_tot = wincl;            // tile total
        }
        __syncthreads();
        int excl = s_off + wsum[wid] + incl - v;
        if (i < Nn) { row_start[i] = excl; cur[i] = 0; }
        __syncthreads();
        if (tid == 0) s_off += s_tot;
        __syncthreads();
    }
    if (threadIdx.x == 0) row_start[Nn] = s_off;
}

__global__ __launch_bounds__(256) void k_place(
    const int* __restrict__ edst, const int* __restrict__ row_start,
    int* __restrict__ cur, int* __restrict__ perm, int Ecnt)
{
    int e = blockIdx.x * 256 + threadIdx.x;
    if (e < Ecnt) {
        int d = edst[e];
        int pos = row_start[d] + atomicAdd(&cur[d], 1);
        perm[pos] = e;
    }
}

// ---------------- kernel 1: node precompute f_s, f_v ----------------
template<bool BF>
__device__ __forceinline__ void node_pre_body(
    const void* __restrict__ ns, const void* __restrict__ nv,
    const void* __restrict__ attr,
    const float* __restrict__ Wl1s, const float* __restrict__ Wl1v,
    float* __restrict__ f_s, float* __restrict__ f_v, int Nn)
{
    int i = blockIdx.x * 256 + threadIdx.x;
    int stotal = Nn * MUL0;
    if (i < stotal) {
        int n = i >> 6, j = i & 63;
        float a = 0.f;
        #pragma unroll
        for (int u = 0; u < MUL0; u++)
            a = fmaf(ldf<BF>(ns, (size_t)n * MUL0 + u), Wl1s[u * MUL0 + j], a);
        f_s[i] = a * ldf<BF>(attr, n);
    } else {
        int m = i - stotal;
        if (m >= Nn * MUL1 * 3) return;
        int n = m / 96; int idx = m - n * 96;
        int vi = idx / 3; int c = idx - vi * 3;
        float a = 0.f;
        #pragma unroll
        for (int u = 0; u < MUL1; u++)
            a = fmaf(ldf<BF>(nv, (size_t)n * 96 + u * 3 + c), Wl1v[u * MUL1 + vi], a);
        f_v[m] = a * ldf<BF>(attr, n);
    }
}
__global__ __launch_bounds__(256) void k_node_pre(
    const void* ns, const void* nv, const void* attr,
    const float* Wl1s, const float* Wl1v,
    float* f_s, float* f_v, int Nn, const int* flag)
{
    if (*flag) node_pre_body<true >(ns, nv, attr, Wl1s, Wl1v, f_s, f_v, Nn);
    else       node_pre_body<false>(ns, nv, attr, Wl1s, Wl1v, f_s, f_v, Nn);
}

// ---------------- kernel 2: dst-grouped edge aggregation ----------------
// workgroup owns GNODES consecutive dst nodes; edges come from the dst-sorted
// perm array (contiguous slice). Accumulate into LDS (ds_add_f32), write agg
// once per node. Fused angle epilogue.
#define ACC_STRIDE 481   // 480 feats + 1 pad: 16 dst-locals -> 16 distinct banks

template<bool BF>
__device__ void edge_agg_body(
    const void* __restrict__ escal, const void* __restrict__ eattr,
    const void* __restrict__ attr,
    const int* __restrict__ esrc, const int* __restrict__ edst,
    const int* __restrict__ row_start, const int* __restrict__ perm,
    const float* __restrict__ W1f, const float* __restrict__ W2f,
    const float* __restrict__ Wl3,
    const float* __restrict__ f_s, const float* __restrict__ f_v,
    float* __restrict__ agg_s, float* __restrict__ agg_v,
    float* __restrict__ cosb, float* __restrict__ sinb, int Nn,
    unsigned int* __restrict__ hbuf, float* __restrict__ accum)
{
    const int tid   = threadIdx.x;
    const int gbase = blockIdx.x * GNODES;
    const int gend  = (gbase + GNODES < Nn) ? (gbase + GNODES) : Nn;

    // zero LDS accumulator
    for (int i = tid; i < GNODES * ACC_STRIDE; i += 256) accum[i] = 0.f;
    __syncthreads();

    const int e_start = row_start[gbase];
    const int e_end   = row_start[gend];

    for (int base = e_start; base < e_end; base += 256) {
        const int idx = base + tid;
        if (idx >= e_end) continue;          // no barrier below: free divergence
        const int e   = perm[idx];
        const int src = esrc[e];
        const int dl  = edst[e] - gbase;     // 0..15

        float es[NBASIS];
        #pragma unroll
        for (int k = 0; k < NBASIS; k++) es[k] = ldf<BF>(escal, (size_t)e * NBASIS + k);
        const float y0  = ldf<BF>(eattr, (size_t)e * 4 + 0);
        const float y1x = ldf<BF>(eattr, (size_t)e * 4 + 1);
        const float y1y = ldf<BF>(eattr, (size_t)e * 4 + 2);
        const float y1z = ldf<BF>(eattr, (size_t)e * 4 + 3);

        // ---- FC1: rows 0..63 -> LDS bf16 pairs; rows 64..99 -> 36 VGPRs ----
        float hr[36];
#define FC1_LDS(JB) do {                                                    \
        float acc[32];                                                      \
        _Pragma("unroll") for (int j = 0; j < 32; j++) acc[j] = 0.f;        \
        _Pragma("unroll") for (int k = 0; k < NBASIS; k++) {                \
            float ek = es[k];                                               \
            _Pragma("unroll") for (int j = 0; j < 32; j++)                  \
                acc[j] = fmaf(ek, W1f[k * FCH + (JB) + j], acc[j]);         \
        }                                                                   \
        _Pragma("unroll") for (int j = 0; j < 32; j += 2) {                 \
            float a = fast_silu(acc[j]);                                    \
            float b = fast_silu(acc[j + 1]);                                \
            hbuf[(((JB) + j) >> 1) * 256 + tid] =                           \
                (unsigned int)f2bf(a) | ((unsigned int)f2bf(b) << 16);      \
        }                                                                   \
    } while (0)
        FC1_LDS(0);
        FC1_LDS(32);
#undef FC1_LDS
        {   // rows 64..95
            float acc[32];
            #pragma unroll
            for (int j = 0; j < 32; j++) acc[j] = 0.f;
            #pragma unroll
            for (int k = 0; k < NBASIS; k++) {
                float ek = es[k];
                #pragma unroll
                for (int j = 0; j < 32; j++)
                    acc[j] = fmaf(ek, W1f[k * FCH + 64 + j], acc[j]);
            }
            #pragma unroll
            for (int j = 0; j < 32; j++) hr[j] = fast_silu(acc[j]);
        }
        {   // rows 96..99
            float acc[4];
            #pragma unroll
            for (int j = 0; j < 4; j++) acc[j] = 0.f;
            #pragma unroll
            for (int k = 0; k < NBASIS; k++) {
                float ek = es[k];
                #pragma unroll
                for (int j = 0; j < 4; j++)
                    acc[j] = fmaf(ek, W1f[k * FCH + 96 + j], acc[j]);
            }
            #pragma unroll
            for (int j = 0; j < 4; j++) hr[32 + j] = fast_silu(acc[j]);
        }

        // ---- FC2 chunk: w[jb..jb+31] ----
        float w[32];
        auto fc2_chunk32 = [&](int jb) {
            #pragma unroll
            for (int j = 0; j < 32; j++) w[j] = 0.f;
            for (int p = 0; p < 32; p++) {              // rows 0..63 from LDS
                unsigned int hw = hbuf[p * 256 + tid];
                float h0 = lo2f(hw);
                float h1 = hi2f(hw);
                const float* r0 = W2f + (size_t)(2 * p) * WNUMEL + jb;  // uniform -> s_load
                #pragma unroll
                for (int j = 0; j < 32; j++)
                    w[j] = fmaf(h0, r0[j], fmaf(h1, r0[WNUMEL + j], w[j]));
            }
            #pragma unroll
            for (int k = 0; k < 36; k++) {              // rows 64..99 from VGPRs
                const float* rk = W2f + (size_t)(64 + k) * WNUMEL + jb;
                float hk = hr[k];
                #pragma unroll
                for (int j = 0; j < 32; j++)
                    w[j] = fmaf(hk, rk[j], w[j]);
            }
        };

        const float invn = 0.25f;                 // 1/sqrt(16)
        const float y0i  = y0 * invn;
        const float* fs_row = f_s + (size_t)src * MUL0;
        const float* fv_row = f_v + (size_t)src * 96;
        float* arow = accum + dl * ACC_STRIDE;

        // Segment A: w00 * s * y0 -> feat 0..63
        for (int j0 = 0; j0 < 64; j0 += 32) {
            fc2_chunk32(j0);
            #pragma unroll
            for (int j = 0; j < 32; j++)
                atomicAdd(&arow[j0 + j], w[j] * fs_row[j0 + j] * y0i);
        }
        // Segment B: w01 * s (x) y1 -> feat 96 + (0..63)*3 + c
        for (int j0 = 0; j0 < 64; j0 += 32) {
            fc2_chunk32(64 + j0);
            #pragma unroll
            for (int j = 0; j < 32; j++) {
                float b = w[j] * fs_row[j0 + j] * invn;
                float* p = arow + 96 + (j0 + j) * 3;
                atomicAdd(p + 0, b * y1x);
                atomicAdd(p + 1, b * y1y);
                atomicAdd(p + 2, b * y1z);
            }
        }
        // Segment C: w10 * v * y0 -> feat 96 + (64..95)*3 + c
        {
            fc2_chunk32(128);
            #pragma unroll
            for (int u = 0; u < 32; u++) {
                float b = w[u] * y0i;
                const float* vp = fv_row + u * 3;
                float* p = arow + 96 + (64 + u) * 3;
                atomicAdd(p + 0, b * vp[0]);
                atomicAdd(p + 1, b * vp[1]);
                atomicAdd(p + 2, b * vp[2]);
            }
        }
        // Segment D: w11s * dot(v,y1)/sqrt3 -> feat 64..95
        {
            fc2_chunk32(160);
            const float c3 = 0.25f * 0.57735026918962576451f;
            #pragma unroll
            for (int u = 0; u < 32; u++) {
                const float* vp = fv_row + u * 3;
                float d = vp[0] * y1x + vp[1] * y1y + vp[2] * y1z;
                atomicAdd(&arow[64 + u], w[u] * d * c3);
            }
        }
        // Segment E: w11v * cross(v,y1)/sqrt2 -> feat 96 + (96..127)*3 + c
        {
            fc2_chunk32(192);
            const float c2 = 0.25f * 0.70710678118654752440f;
            #pragma unroll
            for (int u = 0; u < 32; u++) {
                const float* vp = fv_row + u * 3;
                float v0 = vp[0], v1 = vp[1], v2 = vp[2];
                float cx = v1 * y1z - v2 * y1y;
                float cy = v2 * y1x - v0 * y1z;
                float cz = v0 * y1y - v1 * y1x;
                float b = w[u] * c2;
                float* p = arow + 96 + (96 + u) * 3;
                atomicAdd(p + 0, b * cx);
                atomicAdd(p + 1, b * cy);
                atomicAdd(p + 2, b * cz);
            }
        }
    }
    __syncthreads();

    // writeback: agg_s / agg_v (each node owned exclusively by this wg)
    for (int i = tid; i < GNODES * 480; i += 256) {
        int dl = i / 480, f = i - dl * 480;
        int n = gbase + dl;
        if (n >= Nn) continue;
        float v = accum[dl * ACC_STRIDE + f];
        if (f < 96) agg_s[(size_t)n * MIDS + f] = v;
        else        agg_v[(size_t)n * (MIDV * 3) + (f - 96)] = v;
    }
    // fused angle epilogue
    if (tid < GNODES) {
        int n = gbase + tid;
        if (n < Nn) {
            const float* ar = accum + tid * ACC_STRIDE;
            float a = 0.f;
            #pragma unroll
            for (int f = 0; f < MIDS; f++) a = fmaf(ar[f], Wl3[f], a);
            a = 0.1f * a * ldf<BF>(attr, n);
            cosb[n] = __cosf(a);
            sinb[n] = __sinf(a);
        }
    }
}

__global__ __launch_bounds__(256) void k_edge_agg(
    const void* escal, const void* eattr, const void* attr,
    const int* esrc, const int* edst,
    const int* row_start, const int* perm,
    const float* W1f, const float* W2f, const float* Wl3,
    const float* f_s, const float* f_v,
    float* agg_s, float* agg_v, float* cosb, float* sinb, int Nn,
    const int* flag)
{
    __shared__ unsigned int hbuf[32 * 256];        // 32 KB
    __shared__ float accum[GNODES * ACC_STRIDE];   // 30.8 KB -> total 63.5 KB
    if (*flag) edge_agg_body<true >(escal, eattr, attr, esrc, edst, row_start, perm,
                                    W1f, W2f, Wl3, f_s, f_v, agg_s, agg_v, cosb, sinb, Nn,
                                    hbuf, accum);
    else       edge_agg_body<false>(escal, eattr, attr, esrc, edst, row_start, perm,
                                    W1f, W2f, Wl3, f_s, f_v, agg_s, agg_v, cosb, sinb, Nn,
                                    hbuf, accum);
}

// ---------------- kernel 4: final output ----------------
template<bool BF>
__device__ __forceinline__ void final_body(
    const void* __restrict__ ns, const void* __restrict__ nv,
    const void* __restrict__ attr,
    const float* __restrict__ Wscs, const float* __restrict__ Wscv,
    const float* __restrict__ Wl2s, const float* __restrict__ Wl2v,
    const float* __restrict__ agg_s, const float* __restrict__ agg_v,
    const float* __restrict__ cosb, const float* __restrict__ sinb,
    void* __restrict__ out, int Nn)
{
    int i = blockIdx.x * 256 + threadIdx.x;
    int stotal = Nn * MUL0;
    if (i < stotal) {
        int n = i >> 6, j = i & 63;
        const float* ar = agg_s + (size_t)n * MIDS;
        float a1 = 0.f, a2 = 0.f;
        #pragma unroll
        for (int u = 0; u < MUL0; u++)
            a1 = fmaf(ldf<BF>(ns, (size_t)n * MUL0 + u), Wscs[u * MUL0 + j], a1);
        #pragma unroll
        for (int u = 0; u < MIDS; u++) a2 = fmaf(ar[u], Wl2s[u * MUL0 + j], a2);
        float o = ldf<BF>(attr, n) * (cosb[n] * a1 + sinb[n] * a2);
        stf<BF>(out, (size_t)n * 160 + j, o);
    } else {
        int m = i - stotal;
        if (m >= Nn * 96) return;
        int n = m / 96; int idx = m - n * 96;
        int vi = idx / 3; int c = idx - vi * 3;
        const float* ar = agg_v + (size_t)n * (MIDV * 3);
        float a1 = 0.f, a2 = 0.f;
        #pragma unroll
        for (int u = 0; u < MUL1; u++)
            a1 = fmaf(ldf<BF>(nv, (size_t)n * 96 + u * 3 + c), Wscv[u * MUL1 + vi], a1);
        #pragma unroll
        for (int u = 0; u < MIDV; u++) a2 = fmaf(ar[u * 3 + c], Wl2v[u * MUL1 + vi], a2);
        float o = ldf<BF>(attr, n) * (cosb[n] * a1 + sinb[n] * a2);
        stf<BF>(out, (size_t)n * 160 + 64 + idx, o);
    }
}
__global__ __launch_bounds__(256) void k_final(
    const void* ns, const void* nv, const void* attr,
    const float* Wscs, const float* Wscv,
    const float* Wl2s, const float* Wl2v,
    const float* agg_s, const float* agg_v,
    const float* cosb, const float* sinb,
    void* out, int Nn, const int* flag)
{
    if (*flag) final_body<true >(ns, nv, attr, Wscs, Wscv, Wl2s, Wl2v, agg_s, agg_v, cosb, sinb, out, Nn);
    else       final_body<false>(ns, nv, attr, Wscs, Wscv, Wl2s, Wl2v, agg_s, agg_v, cosb, sinb, out, Nn);
}

// ---------------- launch ----------------
extern "C" void kernel_launch(void* const* d_in, const int* in_sizes, int n_in,
                              void* d_out, int out_size, void* d_ws, size_t ws_size,
                              hipStream_t stream)
{
    const void* ns    = d_in[0];
    const void* nv    = d_in[1];
    const void* attr  = d_in[2];
    const int*  esrc  = (const int*)d_in[3];
    const int*  edst  = (const int*)d_in[4];
    const void* eattr = d_in[5];
    const void* escal = d_in[6];

    const int Nn   = in_sizes[2];   // node_attr is (N,1)
    const int Ecnt = in_sizes[3];   // edge_src is (E,)

    float* ws = (float*)d_ws;
    int* flag = (int*)(ws + OFF_FLAG);
    const size_t OFF_FS   = OFF_DYN;
    const size_t OFF_FV   = OFF_FS   + (size_t)Nn * 64;
    const size_t OFF_AGGS = OFF_FV   + (size_t)Nn * 96;
    const size_t OFF_AGGV = OFF_AGGS + (size_t)Nn * 96;
    const size_t OFF_COS  = OFF_AGGV + (size_t)Nn * 384;
    const size_t OFF_SIN  = OFF_COS  + (size_t)Nn;
    const size_t OFF_CNT  = OFF_SIN  + (size_t)Nn;       // int[Nn]
    const size_t OFF_ROW  = OFF_CNT  + (size_t)Nn;       // int[Nn+1]
    const size_t OFF_CUR  = OFF_ROW  + (size_t)Nn + 1;   // int[Nn]
    const size_t OFF_PERM = OFF_CUR  + (size_t)Nn;       // int[Ecnt]

    int* cnt       = (int*)(ws + OFF_CNT);
    int* row_start = (int*)(ws + OFF_ROW);
    int* cur       = (int*)(ws + OFF_CUR);
    int* perm      = (int*)(ws + OFF_PERM);

    k_probe<<<1, 64, 0, stream>>>((const unsigned int*)attr, flag);

    k_convert<<<(OFF_WEND + 255) / 256, 256, 0, stream>>>(
        d_in[7], d_in[8], d_in[9], d_in[10], d_in[11], d_in[12],
        d_in[13], d_in[14], d_in[15], ws, flag);

    // CSR by dst
    hipMemsetAsync(cnt, 0, (size_t)Nn * sizeof(int), stream);
    k_hist<<<(Ecnt + 255) / 256, 256, 0, stream>>>(edst, cnt, Ecnt);
    k_scan<<<1, 1024, 0, stream>>>(cnt, row_start, cur, Nn);
    k_place<<<(Ecnt + 255) / 256, 256, 0, stream>>>(edst, row_start, cur, perm, Ecnt);

    k_node_pre<<<((Nn * 160) + 255) / 256, 256, 0, stream>>>(
        ns, nv, attr, ws + OFF_WL1S, ws + OFF_WL1V,
        ws + OFF_FS, ws + OFF_FV, Nn, flag);

    k_edge_agg<<<(Nn + GNODES - 1) / GNODES, 256, 0, stream>>>(
        escal, eattr, attr, esrc, edst, row_start, perm,
        ws + OFF_W1, ws + OFF_W2, ws + OFF_WL3,
        ws + OFF_FS, ws + OFF_FV,
        ws + OFF_AGGS, ws + OFF_AGGV, ws + OFF_COS, ws + OFF_SIN, Nn, flag);

    k_final<<<((Nn * 160) + 255) / 256, 256, 0, stream>>>(
        ns, nv, attr,
        ws + OFF_WSCS, ws + OFF_WSCV, ws + OFF_WL2S, ws + OFF_WL2V,
        ws + OFF_AGGS, ws + OFF_AGGV, ws + OFF_COS, ws + OFF_SIN,
        (void*)d_out, Nn, flag);
}